// Round 3
// baseline (116.858 us; speedup 1.0000x reference)
//
#include <hip/hip_runtime.h>
#include <math.h>

#define DNUM 1024
#define CNUM 32000
#define NT 512             // 8 waves/block
#define GRID DNUM          // 1024 blocks, 1 row each -> 4 resident blocks/CU
#define KC 4               // coarse bins (1.35 sigma each), span [-0.5s, +4.9s]
#define KF 8               // fine bins   (0.169 sigma each)
#define NQ (CNUM / 4)      // 8000 4-class chunks
#define NFULL (NQ / NT)    // 15 full iterations
#define TAILN (NQ - NFULL*NT) // 320 (wave-aligned: no intra-wave divergence)

#define L2E 1.4426950408889634f
#define LN2 0.6931471805599453f

typedef float v2f __attribute__((ext_vector_type(2)));

__device__ __forceinline__ v2f splat2(float s) { v2f v; v.x = s; v.y = s; return v; }

__device__ __forceinline__ float wave_red_sum(float v) {
    #pragma unroll
    for (int o = 32; o > 0; o >>= 1) v += __shfl_down(v, o, 64);
    return v;
}

// One block = ONE row, two streaming passes over L2-resident e1/e3.
// Round-3 changes vs round-2 (which measured 59us, VALUBusy 59%, occ 61%):
// (a) pass-1 coarse histogram -> register BIN-MOMENTS q_k = sum(e2 * b^k),
//     k=0..3; bin sums recovered exactly via inverse Vandermonde on nodes
//     {0,1,2,3} by one thread. Removes all pass-1 LDS RMW chains (ds_read->
//     v_add->ds_write serialized per iteration), the pass-1 pool zeroing,
//     one barrier, and the 256-thread histogram reduce.
// (b) software-pipelined global loads in both passes (prefetch next chunk
//     into regs during body; clamped tail index). Round-1 proved the
//     prefetch harmless -- the regression there was unsafeAtomicAdd->FLAT.
// (c) LDS pool is pass-2-only now: 32 KB, 4 blocks/CU (32 waves/CU).
// Histogram updates in pass 2 stay plain += (per-thread-private slots).
__global__ __launch_bounds__(NT, 8) void akl_rows(
    const float* __restrict__ h1, const float* __restrict__ e1,
    const float* __restrict__ h3, const float* __restrict__ e3,
    float* __restrict__ out)
{
    const int tid  = threadIdx.x;
    const int lane = tid & 63, wid = tid >> 6;   // 8 waves
    const int row = blockIdx.x;

    __shared__ float pool[8192];   // 32 KB: P2 fine e2: base 0; fine gap: base 4096
    __shared__ float red[56];      // pass1: 7 values x 8 waves; pass2 reuses 16
    __shared__ float shFP[KF], shFG[KF];
    __shared__ float shA[7];       // c, thr, fkl, rkl, icwF, c0Fs, Spre

    // Per-row coefficients, log2 domain (block-uniform -> scalar regs)
    const float a1L = h1[2*row] * L2E,  b1L = h1[2*row+1] * L2E;
    const float a2L = h3[2*row] * L2E,  b2L = h3[2*row+1] * L2E;
    const float mh1L = 6.0f * (fabsf(a1L) + fabsf(b1L));   // safe shift
    const float mh2L = 6.0f * (fabsf(a2L) + fabsf(b2L));
    const float spC = fmaxf(sqrtf(a2L*a2L + b2L*b2L), 1e-6f);
    const float icwC = 1.0f / (1.35f * spC);       // 4 cells over [-0.5s, +4.9s]
    const float c0C = 0.5f/1.35f + mh2L*icwC;      // cb=(int)(l2s*icwC + c0C)

    const float4* __restrict__ E1 = (const float4*)e1;
    const float4* __restrict__ E3 = (const float4*)e3;

    const int cnt = NFULL + ((tid < TAILN) ? 1 : 0);

    // ===== Pass 1: moments + coarse bin-moments (all-register) =====
    v2f U1v = splat2(0.f), S1v = splat2(0.f), S2v = splat2(0.f);
    v2f q0v = splat2(0.f), q1v = splat2(0.f), q2v = splat2(0.f), q3v = splat2(0.f);

    {
        const v2f a1v = splat2(a1L), b1v = splat2(b1L);
        const v2f a2v = splat2(a2L), b2v = splat2(b2L);
        const v2f m1v = splat2(-mh1L), m2v = splat2(-mh2L);
        const v2f icv = splat2(icwC), c0v = splat2(c0C);
        float4 cA0 = E1[2*tid], cA1 = E1[2*tid+1];
        float4 cB0 = E3[2*tid], cB1 = E3[2*tid+1];
        #pragma unroll 1
        for (int it = 0; it < cnt; ++it) {
            const int jn = (it+1 < cnt) ? ((it+1)*NT + tid) : tid;  // clamped
            float4 nA0 = E1[2*jn], nA1 = E1[2*jn+1];
            float4 nB0 = E3[2*jn], nB1 = E3[2*jn+1];
            #pragma unroll
            for (int p = 0; p < 2; p++) {
                float4 A = p ? cA1 : cA0, B = p ? cB1 : cB0;
                v2f X1; X1.x = A.x; X1.y = A.z;
                v2f Y1; Y1.x = A.y; Y1.y = A.w;
                v2f X3; X3.x = B.x; X3.y = B.z;
                v2f Y3; Y3.x = B.y; Y3.y = B.w;
                v2f l1 = a1v*X1 + (b1v*Y1 + m1v);     // pk_fma
                v2f l2 = a2v*X3 + (b2v*Y3 + m2v);
                v2f e1v; e1v.x = __builtin_amdgcn_exp2f(l1.x);
                         e1v.y = __builtin_amdgcn_exp2f(l1.y);
                v2f e2v; e2v.x = __builtin_amdgcn_exp2f(l2.x);
                         e2v.y = __builtin_amdgcn_exp2f(l2.y);
                v2f dp = l2 - l1;                     // corrected post-pass
                U1v += e1v;
                S1v += e1v * dp;
                S2v += e2v * dp;
                v2f t = l2*icv + c0v;
                // bin index as float, clamped to [0,3]
                v2f bfv;
                bfv.x = truncf(fminf(fmaxf(t.x, 0.f), 3.f));  // med3+trunc
                bfv.y = truncf(fminf(fmaxf(t.y, 0.f), 3.f));
                v2f bf2 = bfv*bfv, bf3 = bf2*bfv;
                q0v += e2v;                            // == U2 contribution
                q1v += e2v * bfv;
                q2v += e2v * bf2;
                q3v += e2v * bf3;
            }
            cA0 = nA0; cA1 = nA1; cB0 = nB0; cB1 = nB1;
        }
    }

    {
        float v0 = wave_red_sum(U1v.x + U1v.y);
        float v1 = wave_red_sum(S1v.x + S1v.y);
        float v2 = wave_red_sum(S2v.x + S2v.y);
        float v3 = wave_red_sum(q0v.x + q0v.y);
        float v4 = wave_red_sum(q1v.x + q1v.y);
        float v5 = wave_red_sum(q2v.x + q2v.y);
        float v6 = wave_red_sum(q3v.x + q3v.y);
        if (lane == 0) {
            red[wid*7 + 0] = v0; red[wid*7 + 1] = v1; red[wid*7 + 2] = v2;
            red[wid*7 + 3] = v3; red[wid*7 + 4] = v4; red[wid*7 + 5] = v5;
            red[wid*7 + 6] = v6;
        }
    }
    // zero pool for the fine pass (pass 1 never touches it)
    for (int i = tid; i < 8192; i += NT) pool[i] = 0.f;
    __syncthreads();                                                   // B1

    // ---- Row params + coarse crossing cell (one thread) ----
    if (tid == 0) {
        float U1s = 0, S1s = 0, S2s = 0, Q0 = 0, Q1 = 0, Q2 = 0, Q3 = 0;
        for (int w = 0; w < 8; w++) {
            U1s += red[w*7 + 0];
            S1s += red[w*7 + 1];
            S2s += red[w*7 + 2];
            Q0  += red[w*7 + 3];
            Q1  += red[w*7 + 4];
            Q2  += red[w*7 + 5];
            Q3  += red[w*7 + 6];
        }
        float U2s = Q0;
        // exact bin sums via inverse Vandermonde on nodes {0,1,2,3}
        float sb[KC];
        sb[0] = Q0 - (11.f*Q1 - 6.f*Q2 + Q3) * (1.f/6.f);
        sb[1] = (6.f*Q1 - 5.f*Q2 + Q3) * 0.5f;
        sb[2] = (4.f*Q2 - 3.f*Q1 - Q3) * 0.5f;
        sb[3] = (2.f*Q1 - 3.f*Q2 + Q3) * (1.f/6.f);
        float dmh = mh2L - mh1L;
        S1s += dmh * U1s;                        // exact shift correction
        S2s += dmh * U2s;
        float M1 = mh1L + __builtin_amdgcn_logf(U1s);
        float M2 = mh2L + __builtin_amdgcn_logf(U2s);
        float delta = M2 - M1;
        float thr = 0.5f * U2s;
        float S = 0.f; int bsel = KC-1;
        for (int i = 0; i < KC; i++) {
            float m = sb[i];
            if (S + m >= thr) { bsel = i; break; }
            S += m;
        }
        float wc  = 1.35f * spC;                 // coarse cell width
        float loS_s = fmaf((float)bsel, wc, -0.5f*spC) - mh2L;  // shifted space
        float icwF = (float)KF / wc;
        shA[0] = U2s / U1s;                      // c (gap scale fold)
        shA[1] = thr;
        shA[2] = LN2 * (S2s/U2s - delta);        // fkl
        shA[3] = LN2 * (delta - S1s/U1s);        // rkl
        shA[4] = icwF;
        shA[5] = -loS_s * icwF;                  // c0Fs: t=l2s*icwF+c0Fs
        shA[6] = S;                              // Spre (unnorm prefix below cell)
    }
    __syncthreads();                                                   // B3

    // ================= Pass 2: gap stats + fine partition ===================
    const float cR = shA[0], icwF = shA[4], c0F = shA[5];
    v2f gtv = splat2(0.f), Gpv = splat2(0.f);

    {
        const v2f a1v = splat2(a1L), b1v = splat2(b1L);
        const v2f a2v = splat2(a2L), b2v = splat2(b2L);
        const v2f m1v = splat2(-mh1L), m2v = splat2(-mh2L);
        const v2f cv = splat2(-cR);
        const v2f icv = splat2(icwF), c0v = splat2(c0F);
        float* HP = pool;
        float* HG = pool + 4096;
        float4 cA0 = E1[2*tid], cA1 = E1[2*tid+1];
        float4 cB0 = E3[2*tid], cB1 = E3[2*tid+1];
        #pragma unroll 1
        for (int it = 0; it < cnt; ++it) {
            const int jn = (it+1 < cnt) ? ((it+1)*NT + tid) : tid;  // clamped
            float4 nA0 = E1[2*jn], nA1 = E1[2*jn+1];
            float4 nB0 = E3[2*jn], nB1 = E3[2*jn+1];
            #pragma unroll
            for (int p = 0; p < 2; p++) {
                float4 A = p ? cA1 : cA0, B = p ? cB1 : cB0;
                v2f X1; X1.x = A.x; X1.y = A.z;
                v2f Y1; Y1.x = A.y; Y1.y = A.w;
                v2f X3; X3.x = B.x; X3.y = B.z;
                v2f Y3; Y3.x = B.y; Y3.y = B.w;
                v2f l1 = a1v*X1 + (b1v*Y1 + m1v);
                v2f l2 = a2v*X3 + (b2v*Y3 + m2v);
                v2f e1v; e1v.x = __builtin_amdgcn_exp2f(l1.x);
                         e1v.y = __builtin_amdgcn_exp2f(l1.y);
                v2f e2v; e2v.x = __builtin_amdgcn_exp2f(l2.x);
                         e2v.y = __builtin_amdgcn_exp2f(l2.y);
                v2f d = cv*e1v + e2v;                // e2 - c*e1 (pk_fma)
                v2f gap; gap.x = fabsf(d.x); gap.y = fabsf(d.y);
                gtv += gap;
                v2f t = l2*icv + c0v;
                Gpv.x += (t.x < 0.f) ? gap.x : 0.f;
                Gpv.y += (t.y < 0.f) ? gap.y : 0.f;
                if (t.x >= 0.f && t.x < (float)KF) {   // ~1% of elements
                    int fb = (int)t.x;
                    HP[fb*NT + tid] += e2v.x;
                    HG[fb*NT + tid] += gap.x;
                }
                if (t.y >= 0.f && t.y < (float)KF) {
                    int fb = (int)t.y;
                    HP[fb*NT + tid] += e2v.y;
                    HG[fb*NT + tid] += gap.y;
                }
            }
            cA0 = nA0; cA1 = nA1; cB0 = nB0; cB1 = nB1;
        }
    }

    {
        float a = wave_red_sum(gtv.x + gtv.y);
        float b = wave_red_sum(Gpv.x + Gpv.y);
        if (lane == 0) { red[wid*2 + 0] = a; red[wid*2 + 1] = b; }
    }
    __syncthreads();                                                   // B4

    // ---- Reduce fine histograms: 16 groups x 32 lanes ----
    {
        int grp = tid >> 5, l32 = tid & 31;      // 16 groups
        int isG = grp >> 3, b = grp & 7;         // 0: P, 1: G
        const float* H = pool + isG*4096 + b*512;
        float s = 0.f;
        #pragma unroll
        for (int t = 0; t < NT/32; t++) s += H[l32 + t*32];
        #pragma unroll
        for (int o = 16; o > 0; o >>= 1) s += __shfl_down(s, o, 32);
        if (l32 == 0) {
            if (isG) shFG[b] = s; else shFP[b] = s;
        }
    }
    __syncthreads();                                                   // B5

    // ---- Walk fine bins, secant-interpolate 0.5 crossing, output ----
    if (tid == 0) {
        float gts = 0, Gp = 0;
        for (int w = 0; w < 8; w++) {
            gts += red[w*2 + 0];
            Gp  += red[w*2 + 1];
        }
        float thr = shA[1], fkl = shA[2], rkl = shA[3];
        float S = shA[6], G = Gp;
        bool done = false;
        #pragma unroll
        for (int i = 0; i < KF; i++) {
            if (!done) {
                float p = shFP[i], g = shFG[i];
                float ns = S + p;
                if (ns >= thr) {
                    float f = (thr - S) / fmaxf(p, 1e-30f);
                    f = fminf(fmaxf(f, 0.f), 1.f);
                    G += f * g;
                    done = true;
                } else { S = ns; G += g; }
            }
        }
        float gl = G;                    // g_tail (unnormalized: scale cancels)
        float gh = gts - gl;             // g_head
        float akl = (gh*fkl + gl*rkl) / gts;
        unsafeAtomicAdd(out, akl * (1.0f/(float)DNUM));
    }
}

extern "C" void kernel_launch(void* const* d_in, const int* in_sizes, int n_in,
                              void* d_out, int out_size, void* d_ws, size_t ws_size,
                              hipStream_t stream) {
    const float* h1 = (const float*)d_in[0];
    const float* e1 = (const float*)d_in[1];
    const float* h3 = (const float*)d_in[2];
    const float* e3 = (const float*)d_in[3];
    hipMemsetAsync(d_out, 0, sizeof(float), stream);   // capture-safe
    akl_rows<<<GRID, NT, 0, stream>>>(h1, e1, h3, e3, (float*)d_out);
}